// Round 8
// baseline (274.060 us; speedup 1.0000x reference)
//
#include <hip/hip_runtime.h>
#include <hip/hip_bf16.h>
#include <math.h>

// IDSCT2: out[b,u,v] = sum_{p,q} x[b,p,q] * S[u,p] * C[v,q]
// R13: parity-folded GEMM (R8 math, R9 geometry: 128x256, 2x4 waves,
// dual parity per wave, in-wave fold epilogue) with B DIRECT-TO-REGISTER:
// NT layout means a B-fragment (B[n][k..k+7] per lane) is 16 contiguous
// global bytes = the MFMA operand layout. B skips LDS entirely (loads
// hit L1/L2: 1 MiB slice/block, re-read 8x, wr0/wr1 waves share lines).
// Only A is LDS-staged (4-way reuse across wc), double-buffered 32 KiB.
// Why: R8-R12 all ran at ~2.2x their LDS floor with MfmaUtil 24-29%;
// R12 proved occupancy doesn't help (LDS pipe shared). B-direct halves
// LDS reads and cuts glds writes 3x, shifting work to the idle vmem
// pipe (HBM 9%, L2 far from ceiling).
// Per tile: {STG A(t+1): 2 glds -> buf n; LDB B(t+1): 8 dwordx4 -> reg
// set n; LDF A(t): 8 ds_read_b128 buf c; 32 MFMA (compiler auto-waits
// B(t) via vmcnt, A(t) via lgkmcnt); vmcnt(8) retires A(t+1) [newest 8
// ops = B(t+1), so A(t+1) is strictly older -- robust to interleave,
// and load-splitting only over-waits]; s_barrier publishes}.
// WAR safe: buf n's readers (tile t-1) complete before the t-1 barrier;
// its writers issue after. "memory" clobber on the waits fences each
// tile's issue-set so vmcnt counts can't leak across tiles.
//   C[2047-v,q] = (-1)^q C[v,q];  S[2047-u,p] = -(-1)^p S[u,p]
// pass1: Et/Ot (even/odd q), tT[v']=Et+Ot, tT[2047-v']=Et-Ot, output
// p-parity-split (tTe/tTo) to feed pass2 directly.
// pass2: E2/O2 (even/odd p), out[u']=E2+O2, out[2047-u']=O2-E2 (fp32).
// A swizzle (both-sides, rule #21): 64B rows = 4 chunks; slot =
// chunk ^ ((row>>1)&3) via pre-swizzled global src (linear glds dest);
// ds_read applies the same XOR -> conflict-free b128 (R8-R11 measured 0).

#define BM 128   // output rows per block (v' / u')
#define BN 256   // output cols per block (p / v)
#define BK 32
#define KDIM 1024

typedef __bf16 bf16x8 __attribute__((ext_vector_type(8)));
typedef __bf16 bf16x4 __attribute__((ext_vector_type(4)));
typedef float floatx4 __attribute__((ext_vector_type(4)));

__device__ __forceinline__ void async_ld16(const void* g, void* l) {
    __builtin_amdgcn_global_load_lds(
        (__attribute__((address_space(1))) void*)(g),
        (__attribute__((address_space(3))) void*)(l), 16, 0, 0);
}

#define BARX() __builtin_amdgcn_s_barrier()
#define VM8() asm volatile("s_waitcnt vmcnt(8)" ::: "memory")

// Basis + deinterleave-convert x. Integer phase mod 8192 keeps trig arg
// exact: arg = pi/4096 * phase.
//   Ce[v',j]=cos(pi(2v'+1)(2j)/4096)   Co: (2j+1)
//   Se[u',m]=sin(pi(2u'+1)(2m)/4096)   So: (2m+1)
//   xe[b,p,m]=x[b,p,2m]  xo: 2m+1
__global__ void prep_kernel(const float4* __restrict__ x,
                            bf16x4* __restrict__ xe, bf16x4* __restrict__ xo,
                            __bf16* __restrict__ Ce, __bf16* __restrict__ Co,
                            __bf16* __restrict__ Se, __bf16* __restrict__ So) {
    int b = blockIdx.x;
    if (b < 4096) {  // 1M basis entries
        int idx = b * 256 + threadIdx.x;
        int vp = idx >> 10;
        int j = idx & 1023;
        int pe = ((2 * vp + 1) * (2 * j)) & 8191;
        int po = ((2 * vp + 1) * (2 * j + 1)) & 8191;
        float ae = (float)pe * 7.669903939428206e-04f;  // pi/4096
        float ao = (float)po * 7.669903939428206e-04f;
        float se, ce, so, co;
        __sincosf(ae, &se, &ce);
        __sincosf(ao, &so, &co);
        Ce[idx] = (__bf16)ce;
        Co[idx] = (__bf16)co;
        Se[idx] = (__bf16)se;
        So[idx] = (__bf16)so;
    } else {  // 2M threads, 8 floats each
        int g = (b - 4096) * 256 + threadIdx.x;
        float4 v0 = x[2 * g];
        float4 v1 = x[2 * g + 1];
        bf16x4 e, o;
        e[0] = (__bf16)v0.x; e[1] = (__bf16)v0.z;
        e[2] = (__bf16)v1.x; e[3] = (__bf16)v1.z;
        o[0] = (__bf16)v0.y; o[1] = (__bf16)v0.w;
        o[2] = (__bf16)v1.y; o[3] = (__bf16)v1.w;
        xe[g] = e;
        xo[g] = o;
    }
}

// Parity-folded NT GEMM. A{e,o}: [1024][1024] (shared over z).
// B{e,o}: [z][2048][1024]. PASS=1: D0/D1 = tTe/tTo [z][2048][1024] bf16,
// fold rows v', 2047-v' and split output cols by parity.
// PASS=2: Df = out [z][2048][2048] fp32, fold rows u', 2047-u'.
template <int PASS>
__global__ void __launch_bounds__(512, 2) gemm_eo(
    const __bf16* __restrict__ Ae, const __bf16* __restrict__ Ao,
    const __bf16* __restrict__ Be, const __bf16* __restrict__ Bo,
    __bf16* __restrict__ D0, __bf16* __restrict__ D1,
    float* __restrict__ Df) {
    // per buffer: Ae[128*32] + Ao[128*32] = 8192 elems; 2 bufs = 32 KiB
    __shared__ __bf16 lds[2][8192];
    constexpr int OFF_AE = 0, OFF_AO = 4096;

    const int tid = threadIdx.x;
    const int lane = tid & 63;
    const int wave = tid >> 6;   // 0..7
    const int wr = wave >> 2;    // 0..1: row offset wr*64
    const int wc = wave & 3;     // 0..3: col offset wc*64

    const size_t zB = (size_t)blockIdx.z * 2048 * 1024;
    Be += zB; Bo += zB;

    const int row0 = blockIdx.y * BM;   // v'/u' in [0,1024)
    const int col0 = blockIdx.x * BN;   // p/v  in [0,2048)

    // ---- A staging: one glds = 512 thr x 16B = 8 KiB = 128 rows of 64B.
    // Lane slot within each row freely assignable -> global chunk =
    // slot ^ ((row>>1)&3) (involution, shared with the read side).
    const int srow = tid >> 2;
    const int sgc = ((tid & 3) ^ ((srow >> 1) & 3)) * 8;
    const __bf16* aeS = Ae + (size_t)(row0 + srow) * KDIM + sgc;
    const __bf16* aoS = Ao + (size_t)(row0 + srow) * KDIM + sgc;
    const int ldsW = wave << 9;  // wave-uniform dest base (elems)

    auto STG = [&](int s, int kt) {
        async_ld16(aeS + kt * BK, &lds[s][OFF_AE + ldsW]);
        async_ld16(aoS + kt * BK, &lds[s][OFF_AO + ldsW]);
    };

    // ---- A fragment reads: m = lane&15 (+16*frag), k-chunk = lane>>4;
    // stored slot = chunk ^ ((fr>>1)&3) -> conflict-free b128 (measured 0).
    const int fr = lane & 15;
    const int fc = lane >> 4;
    const int slotOff = (fc ^ ((fr >> 1) & 3)) * 8;
    const int aBase = (wr * 64 + fr) * BK + slotOff;

    // ---- B direct-to-register: frag j of k-tile kt lives at
    // B[(col0 + wc*64 + j*16 + fr)*1024 + kt*32 + fc*8], 16B aligned.
    const __bf16* bE = Be + (size_t)(col0 + wc * 64 + fr) * KDIM + fc * 8;
    const __bf16* bO = Bo + (size_t)(col0 + wc * 64 + fr) * KDIM + fc * 8;

    bf16x8 afE[4], afO[4];
    bf16x8 bfE0[4], bfO0[4], bfE1[4], bfO1[4];  // double-buffered B regs
    floatx4 accE[4][4] = {};
    floatx4 accO[4][4] = {};

    auto LDF = [&](int buf) {
#pragma unroll
        for (int i = 0; i < 4; ++i) {
            afE[i] = *(const bf16x8*)&lds[buf][OFF_AE + aBase + i * 16 * BK];
            afO[i] = *(const bf16x8*)&lds[buf][OFF_AO + aBase + i * 16 * BK];
        }
    };
    auto MMA16 = [&](floatx4(&acc)[4][4], bf16x8(&af)[4], bf16x8(&bf)[4]) {
        __builtin_amdgcn_s_setprio(1);
#pragma unroll
        for (int i = 0; i < 4; ++i)
#pragma unroll
            for (int j = 0; j < 4; ++j)
                acc[i][j] = __builtin_amdgcn_mfma_f32_16x16x32_bf16(
                    af[i], bf[j], acc[i][j], 0, 0, 0);
        __builtin_amdgcn_s_setprio(0);
    };

#define LDB(n, kt)                                                          \
    do {                                                                    \
        _Pragma("unroll")                                                   \
        for (int j = 0; j < 4; ++j) {                                       \
            bfE##n[j] = *(const bf16x8*)&bE[(size_t)j * 16 * KDIM + (kt) * BK]; \
            bfO##n[j] = *(const bf16x8*)&bO[(size_t)j * 16 * KDIM + (kt) * BK]; \
        }                                                                   \
    } while (0)

    // Per tile t (buf c = t&1, n = c^1): stage t+1, compute t.
    // vmcnt(8): newest 8 outstanding = B(t+1) -> A(t+1) glds retired.
#define TILE(c, n, kt1)                           \
    do {                                          \
        STG(n, kt1);                              \
        LDB(n, kt1);                              \
        LDF(c);                                   \
        MMA16(accE, afE, bfE##c);                 \
        MMA16(accO, afO, bfO##c);                 \
        VM8();                                    \
        BARX();                                   \
    } while (0)

    // Prologue: stage tile 0 (2 glds + 8 B-loads); vmcnt(8) retires the
    // A glds (B(0) stays in flight, consumed by tile 0's MMA).
    STG(0, 0);
    LDB(0, 0);
    VM8();
    BARX();

    // 32 K-tiles, unrolled x2 for static buffer/reg-set names.
    for (int i = 0; i < 15; ++i) {
        TILE(0, 1, 2 * i + 1);
        TILE(1, 0, 2 * i + 2);
    }
    TILE(0, 1, 31);  // tile 30, stages tile 31
    // Tile 31: no staging; compiler auto-waits B(31)/lgkm.
    LDF(1);
    MMA16(accE, afE, bfE1);
    MMA16(accO, afO, bfO1);
#undef TILE
#undef LDB

    // Epilogue (R9, verified). C/D layout: col=lane&15, row=(lane>>4)*4+reg.
    const int ecol = lane & 15;
    const int erow = (lane >> 4) * 4;
#pragma unroll
    for (int i = 0; i < 4; ++i)
#pragma unroll
        for (int j = 0; j < 4; ++j)
#pragma unroll
            for (int r = 0; r < 4; ++r) {
                const int gi = row0 + wr * 64 + i * 16 + erow + r;
                const int gj = col0 + wc * 64 + j * 16 + ecol;
                const float e = accE[i][j][r];
                const float o = accO[i][j][r];
                if (PASS == 1) {
                    // tT[gi] = e+o ; tT[2047-gi] = e-o ; split col parity
                    __bf16* base = (gj & 1) ? D1 : D0;
                    base += zB;
                    const size_t m = (size_t)(gj >> 1);
                    base[(size_t)gi * 1024 + m] = (__bf16)(e + o);
                    base[(size_t)(2047 - gi) * 1024 + m] = (__bf16)(e - o);
                } else {
                    // out[gi] = e+o ; out[2047-gi] = o-e
                    float* ob = Df + (size_t)blockIdx.z * 2048 * 2048;
                    ob[(size_t)gi * 2048 + gj] = e + o;
                    ob[(size_t)(2047 - gi) * 2048 + gj] = o - e;
                }
            }
}

extern "C" void kernel_launch(void* const* d_in, const int* in_sizes, int n_in,
                              void* d_out, int out_size, void* d_ws, size_t ws_size,
                              hipStream_t stream) {
    const float* x = (const float*)d_in[0];
    float* out = (float*)d_out;

    const size_t m1 = (size_t)1024 * 1024;  // basis elems (2 MiB each)
    const size_t hm = (size_t)4 * 2048 * 1024;  // half-matrix batch: 8M elems

    // Workspace (72 MiB): Ce,Co,Se,So (8 MiB) | xe,xo (32) | tTe,tTo (32)
    __bf16* Ce = (__bf16*)d_ws;
    __bf16* Co = Ce + m1;
    __bf16* Se = Co + m1;
    __bf16* So = Se + m1;
    __bf16* xe = So + m1;
    __bf16* xo = xe + hm;
    __bf16* tTe = xo + hm;
    __bf16* tTo = tTe + hm;

    // 4096 basis blocks + 8192 deinterleave blocks
    prep_kernel<<<12288, 256, 0, stream>>>((const float4*)x, (bf16x4*)xe,
                                           (bf16x4*)xo, Ce, Co, Se, So);

    dim3 grid(2048 / BN, 1024 / BM, 4);  // (8, 8, 4) = 256 blocks, 1/CU
    // pass1: Et/Ot over q-parity; epilogue folds v' and splits p-parity
    gemm_eo<1><<<grid, 512, 0, stream>>>(Ce, Co, xe, xo, tTe, tTo, nullptr);
    // pass2: E2/O2 over p-parity; epilogue folds u', writes fp32 out
    gemm_eo<2><<<grid, 512, 0, stream>>>(Se, So, tTe, tTo, nullptr, nullptr, out);
}